// Round 5
// baseline (536.638 us; speedup 1.0000x reference)
//
#include <hip/hip_runtime.h>
#include <hip/hip_bf16.h>

// Problem constants (fixed by reference)
#define IN_F   4096
#define OUT_F  4096
#define RANK   16
#define M_TOK  8192          // 4 * 2048 tokens
#define SCALING 2.0f         // ALPHA / RANK = 32/16

typedef __attribute__((ext_vector_type(8))) short short8;   // 8 bf16 = 4 VGPRs
typedef __attribute__((ext_vector_type(4))) float f32x4;
typedef __attribute__((ext_vector_type(4))) float fvec4;
typedef __attribute__((ext_vector_type(4))) int   ivec4;
typedef __attribute__((ext_vector_type(4))) unsigned int uvec4;

// ---------------------------------------------------------------------------
// dequant + LoRA fold: W'[o,i] = (q-8)*scale + 2*(lB@lA)[o,i].
// Each thread owns 4 columns; lA[0:16][c0:c0+4] slice lives in 16 fvec4
// registers; 8 o-rows per block with all 8 q-loads hoisted (MLP).
// 2048 blocks x 256 threads.  ~96 MB HBM -> ~25 us (per the fitted model).
// ---------------------------------------------------------------------------
__global__ __launch_bounds__(256) void dequant_lora(const int* __restrict__ q,
                                                    const float* __restrict__ sc,
                                                    const float* __restrict__ lA,
                                                    const float* __restrict__ lB,
                                                    __hip_bfloat16* __restrict__ W) {
    const int tid = threadIdx.x;
    const int id  = blockIdx.x;              // 0..2047
    const int c0  = (id & 3) * 1024 + tid * 4;
    const int o0  = (id >> 2) * 8;

    ivec4 qv[8];
#pragma unroll
    for (int oo = 0; oo < 8; ++oo)           // all 8 HBM loads in flight
        qv[oo] = __builtin_nontemporal_load(
            (const ivec4*)(q + (size_t)(o0 + oo) * IN_F + c0));

    float sv[8];
#pragma unroll
    for (int oo = 0; oo < 8; ++oo)
        sv[oo] = sc[(o0 + oo) * (IN_F / 64) + (c0 >> 6)];

    fvec4 a[RANK];
#pragma unroll
    for (int r = 0; r < RANK; ++r)           // L2-resident after first touch
        a[r] = *(const fvec4*)(lA + (size_t)r * IN_F + c0);

#pragma unroll
    for (int oo = 0; oo < 8; ++oo) {
        const float* lbo = lB + (size_t)(o0 + oo) * RANK;   // uniform -> SMEM
        float l0 = 0.f, l1 = 0.f, l2 = 0.f, l3 = 0.f;
#pragma unroll
        for (int r = 0; r < RANK; ++r) {
            const float br = lbo[r];
            l0 += br * a[r].x; l1 += br * a[r].y;
            l2 += br * a[r].z; l3 += br * a[r].w;
        }
        const float s = sv[oo];
        union { ushort4 u; __hip_bfloat16 h[4]; } p;
        p.h[0] = __float2bfloat16((float)(qv[oo].x - 8) * s + SCALING * l0);
        p.h[1] = __float2bfloat16((float)(qv[oo].y - 8) * s + SCALING * l1);
        p.h[2] = __float2bfloat16((float)(qv[oo].z - 8) * s + SCALING * l2);
        p.h[3] = __float2bfloat16((float)(qv[oo].w - 8) * s + SCALING * l3);
        *(ushort4*)(W + (size_t)(o0 + oo) * IN_F + c0) = p.u;  // normal store
    }
}

// ---------------------------------------------------------------------------
// GEMM: C[M,N] = X[M,K](fp32, cvt on the fly) * B[N,K]^T(bf16) + bias
// 256x256 tile, BK=64, 512 threads = 8 waves (2M x 4N), 8-phase schedule with
// counted vmcnt (T3+T4), st_16x32 LDS swizzle (T2), setprio (T5), XCD 8x8
// chunk (T1).  A staged from fp32 x directly (no xb intermediate).
//
// ROUND-5 FIX (vs round 4's regression): the per-tile cvt+ds_write of the
// A-slice is moved from AFTER ph3's MFMA cluster to BEFORE it (still inside
// the vmcnt(4)-covered window), pinned with sched_barrier(0).  The ds_writes
// then drain on the DS pipe WHILE the 16 MFMAs run on the matrix pipe; the
// closing lgkmcnt(0) is ~free.  Round 4 paid this cost serially every tile.
//
// vmcnt ledger (steady state, at ph3 wait):
//   queue = [B_lds(t+1) x4 (t-1 ph2/ph3), A_reg(t+1) x8 (t ph0/ph1),
//            B_lds(t+2) x4 (t ph2/ph3)]
//   s_waitcnt vmcnt(4) -> A-regs + B(t+1) landed; B(t+2) stays in flight.
// Write-after-read safety of ASTORE target (next buf A region): last read
// two barriers earlier (tile t-1 ph2); published by ph3's closing barrier.
// ---------------------------------------------------------------------------

__device__ __forceinline__ void load_lds16(const void* g, void* l) {
    __builtin_amdgcn_global_load_lds(
        (const __attribute__((address_space(1))) unsigned int*)g,
        (__attribute__((address_space(3))) unsigned int*)l, 16, 0, 0);
}

#define MFMA_BF16 __builtin_amdgcn_mfma_f32_16x16x32_bf16

__global__ __launch_bounds__(512, 2) void gemm256_8ph(const float* __restrict__ X,
                                                      const __hip_bfloat16* __restrict__ B,
                                                      const float* __restrict__ bias,
                                                      float* __restrict__ C) {
    extern __shared__ __align__(16) char lds[];

    const int tid  = threadIdx.x;
    const int lane = tid & 63;
    const int wave = tid >> 6;

    // T1: XCD swizzle, 8x8 square chunk per XCD (512 wgs % 8 == 0, bijective).
    const int xcd = blockIdx.x & 7;
    const int w64 = blockIdx.x >> 3;               // 0..63 within XCD
    const int tm  = (xcd >> 1) * 8 + (w64 >> 3);   // 0..31 M-tiles
    const int tn  = (xcd & 1) * 8 + (w64 & 7);     // 0..15 N-tiles

    const __hip_bfloat16* Bb = B + (size_t)tn * 256 * IN_F;

    // Staging source mapping (inverse-swizzled, matches read-side XOR):
    // lane l supplies 16B(bf16): row (l>>2), elem ((l&3)*8) ^ (l>=32 ? 16 : 0).
    const int c0   = ((lane & 3) * 8) ^ ((lane >= 32) ? 16 : 0);
    const int arow = (wave >> 1) * 16 + (lane >> 2);     // 0..63
    const int acol = (wave & 1) * 32 + c0;               // 0..63

    // A: per-lane fp32 source bases, one per 64-row slot (hoisted addr math)
    const float* xA = X + (size_t)(tm * 256 + arow) * IN_F + acol;
    const float* xAs[4] = { xA,
                            xA + (size_t)64  * IN_F,
                            xA + (size_t)128 * IN_F,
                            xA + (size_t)192 * IN_F };
    // B: per-lane bf16 source base for global_load_lds
    const size_t off0 = (size_t)arow * IN_F + acol;
    const __hip_bfloat16* qB0 = Bb + off0;
    const __hip_bfloat16* qB1 = Bb + (size_t)128 * IN_F + off0;

    // Swizzled ds_read lane offset within a 1 KiB subtile:
    // logical byte = (lane&15)*64 + (lane>>4)*16 ; swizzle XORs bit5 with bit9.
    const int flo = (lane & 15) * 64 + (((lane >> 4) * 16) ^ ((lane & 8) << 2));

    const int ah = wave >> 2;          // A half this wave reads (rows)
    const int bh = (wave >> 1) & 1;    // B half this wave reads (cols)
    const int bs = (wave & 1) * 4;     // B subtile-row base within half

    // Pre-folded LDS read bases per buffer: every read is base + literal.
    const char* aRd[2] = { lds + ah * 16384 + flo,
                           lds + 65536 + ah * 16384 + flo };
    const char* bRd[2] = { lds + 32768 + bh * 16384 + bs * 2048 + flo,
                           lds + 65536 + 32768 + bh * 16384 + bs * 2048 + flo };

    const int wv1024 = wave * 1024 + lane * 16;   // linear staging dest (bytes)

    f32x4 aR[4][2];    // fp32 A slice in flight: slot = row-block (0,64,128,192)

#define ALOAD(SLOT, TE) do {                                                \
        const float* p_ = xAs[SLOT] + (TE);                                 \
        aR[SLOT][0] = *(const f32x4*)(p_);                                  \
        aR[SLOT][1] = *(const f32x4*)(p_ + 4);                              \
    } while (0)

#define ASTORE(SLOT, NB) do {                                               \
        union { __hip_bfloat16 h[8]; uvec4 v; } pk_;                        \
        pk_.h[0] = __float2bfloat16(aR[SLOT][0].x);                         \
        pk_.h[1] = __float2bfloat16(aR[SLOT][0].y);                         \
        pk_.h[2] = __float2bfloat16(aR[SLOT][0].z);                         \
        pk_.h[3] = __float2bfloat16(aR[SLOT][0].w);                         \
        pk_.h[4] = __float2bfloat16(aR[SLOT][1].x);                         \
        pk_.h[5] = __float2bfloat16(aR[SLOT][1].y);                         \
        pk_.h[6] = __float2bfloat16(aR[SLOT][1].z);                         \
        pk_.h[7] = __float2bfloat16(aR[SLOT][1].w);                         \
        *(uvec4*)(lds + (NB) + (SLOT) * 8192 + wv1024) = pk_.v;             \
    } while (0)

#define STAGE2(ps, te, LO) do {                                             \
        const __hip_bfloat16* g_ = (ps) + (te);                             \
        load_lds16(g_,              lds + (LO) + wv1024);                   \
        load_lds16(g_ + 64 * IN_F,  lds + (LO) + 8192 + wv1024);            \
    } while (0)

    // ---- prologue: A(0) regs x8, B(0) x4, B(1) x4 ----
    ALOAD(0, 0); ALOAD(1, 0); ALOAD(2, 0); ALOAD(3, 0);
    STAGE2(qB0, 0,  32768);
    STAGE2(qB1, 0,  49152);
    STAGE2(qB0, 64, 65536 + 32768);
    STAGE2(qB1, 64, 65536 + 49152);
    asm volatile("s_waitcnt vmcnt(4)" ::: "memory");   // A-regs + B(0) landed
    ASTORE(0, 0); ASTORE(1, 0); ASTORE(2, 0); ASTORE(3, 0);
    asm volatile("s_waitcnt lgkmcnt(0)" ::: "memory"); // ds_writes visible
    __builtin_amdgcn_s_barrier();

    short8 aF[4][2], bAf[2][2], bBf[2][2];
    f32x4 acc[8][4] = {};

#define TILE(T, CBI) do {                                                          \
        const int t1e = (((T) + 1) & 63) << 6;   /* elem offset of tile T+1 */     \
        const int t2e = (((T) + 2) & 63) << 6;                                     \
        /* ---------- phase 0: quadrant (mh0, nh0) ---------- */                   \
        _Pragma("unroll")                                                          \
        for (int i = 0; i < 4; ++i)                                                \
            _Pragma("unroll")                                                      \
            for (int kk = 0; kk < 2; ++kk)                                         \
                aF[i][kk] = *(const short8*)(aRd[CBI] + (i * 2 + kk) * 1024);      \
        _Pragma("unroll")                                                          \
        for (int j = 0; j < 2; ++j)                                                \
            _Pragma("unroll")                                                      \
            for (int kk = 0; kk < 2; ++kk)                                         \
                bAf[j][kk] = *(const short8*)(bRd[CBI] + (j * 2 + kk) * 1024);     \
        ALOAD(0, t1e); ALOAD(1, t1e);                                              \
        __builtin_amdgcn_s_barrier();                                              \
        __builtin_amdgcn_s_setprio(1);                                             \
        _Pragma("unroll")                                                          \
        for (int i = 0; i < 4; ++i)                                                \
            _Pragma("unroll")                                                      \
            for (int j = 0; j < 2; ++j)                                            \
                _Pragma("unroll")                                                  \
                for (int kk = 0; kk < 2; ++kk)                                     \
                    acc[i][j] = MFMA_BF16(aF[i][kk], bAf[j][kk], acc[i][j], 0,0,0);\
        __builtin_amdgcn_s_setprio(0);                                             \
        __builtin_amdgcn_s_barrier();                                              \
        /* ---------- phase 1: quadrant (mh0, nh1) ---------- */                   \
        _Pragma("unroll")                                                          \
        for (int j = 0; j < 2; ++j)                                                \
            _Pragma("unroll")                                                      \
            for (int kk = 0; kk < 2; ++kk)                                         \
                bBf[j][kk] = *(const short8*)(bRd[CBI] + 4096 + (j*2+kk) * 1024);  \
        ALOAD(2, t1e); ALOAD(3, t1e);                                              \
        __builtin_amdgcn_s_barrier();                                              \
        __builtin_amdgcn_s_setprio(1);                                             \
        _Pragma("unroll")                                                          \
        for (int i = 0; i < 4; ++i)                                                \
            _Pragma("unroll")                                                      \
            for (int j = 0; j < 2; ++j)                                            \
                _Pragma("unroll")                                                  \
                for (int kk = 0; kk < 2; ++kk)                                     \
                    acc[i][2+j] = MFMA_BF16(aF[i][kk], bBf[j][kk], acc[i][2+j],0,0,0);\
        __builtin_amdgcn_s_setprio(0);                                             \
        __builtin_amdgcn_s_barrier();                                              \
        /* ---------- phase 2: quadrant (mh1, nh1) ---------- */                   \
        _Pragma("unroll")                                                          \
        for (int i = 0; i < 4; ++i)                                                \
            _Pragma("unroll")                                                      \
            for (int kk = 0; kk < 2; ++kk)                                         \
                aF[i][kk] = *(const short8*)(aRd[CBI] + 8192 + (i*2+kk) * 1024);   \
        STAGE2(qB0, t2e, (CBI) * 65536 + 32768);   /* dead after ph1 */            \
        __builtin_amdgcn_s_barrier();                                              \
        __builtin_amdgcn_s_setprio(1);                                             \
        _Pragma("unroll")                                                          \
        for (int i = 0; i < 4; ++i)                                                \
            _Pragma("unroll")                                                      \
            for (int j = 0; j < 2; ++j)                                            \
                _Pragma("unroll")                                                  \
                for (int kk = 0; kk < 2; ++kk)                                     \
                    acc[4+i][2+j] = MFMA_BF16(aF[i][kk], bBf[j][kk], acc[4+i][2+j],0,0,0);\
        __builtin_amdgcn_s_setprio(0);                                             \
        __builtin_amdgcn_s_barrier();                                              \
        /* ---------- phase 3: quadrant (mh1, nh0) ---------- */                   \
        STAGE2(qB1, t2e, (CBI) * 65536 + 49152);                                   \
        asm volatile("s_waitcnt vmcnt(4)" ::: "memory");  /* A-regs+B(t+1) in */   \
        __builtin_amdgcn_s_barrier();                     /* publish to all */     \
        /* cvt + ds_write A(t+1) FIRST (issue on DS pipe), then MFMA cluster */    \
        ASTORE(0, ((CBI)^1) * 65536); ASTORE(1, ((CBI)^1) * 65536);                \
        ASTORE(2, ((CBI)^1) * 65536); ASTORE(3, ((CBI)^1) * 65536);                \
        __builtin_amdgcn_sched_barrier(0);   /* pin writes before MFMAs */         \
        __builtin_amdgcn_s_setprio(1);                                             \
        _Pragma("unroll")                                                          \
        for (int i = 0; i < 4; ++i)                                                \
            _Pragma("unroll")                                                      \
            for (int j = 0; j < 2; ++j)                                            \
                _Pragma("unroll")                                                  \
                for (int kk = 0; kk < 2; ++kk)                                     \
                    acc[4+i][j] = MFMA_BF16(aF[i][kk], bAf[j][kk], acc[4+i][j],0,0,0);\
        __builtin_amdgcn_s_setprio(0);                                             \
        asm volatile("s_waitcnt lgkmcnt(0)" ::: "memory"); /* writes drained */    \
        __builtin_amdgcn_s_barrier();                                              \
    } while (0)

    for (int tt = 0; tt < 32; ++tt) {      // 2 K-tiles per iter: literal buffers
        TILE(2 * tt,     0);
        TILE(2 * tt + 1, 1);
    }
    asm volatile("s_waitcnt vmcnt(0)" ::: "memory");  // drain wrapped prefetches

    // ---- epilogue: D[row=(lane>>4)*4+r][col=lane&15] per 16x16 frag; +bias ----
    const int qd = lane >> 4;
    const int cl = lane & 15;
    const size_t m_base = (size_t)tm * 256 + (size_t)ah * 128;
    const int    n_base = tn * 256 + (wave & 3) * 64;
#pragma unroll
    for (int fn = 0; fn < 4; ++fn) {
        const int n = n_base + fn * 16 + cl;
        const float bv = bias[n];
#pragma unroll
        for (int fm = 0; fm < 8; ++fm) {
            const size_t m0 = m_base + fm * 16 + qd * 4;
#pragma unroll
            for (int r = 0; r < 4; ++r)
                __builtin_nontemporal_store(acc[fm][fn][r] + bv,
                                            &C[(m0 + r) * OUT_F + n]);
        }
    }
#undef STAGE2
#undef TILE
#undef ALOAD
#undef ASTORE
}

// ---------------------------------------------------------------------------
extern "C" void kernel_launch(void* const* d_in, const int* in_sizes, int n_in,
                              void* d_out, int out_size, void* d_ws, size_t ws_size,
                              hipStream_t stream) {
    const float* x    = (const float*)d_in[0];   // [4,2048,4096] fp32
    const int*   qc   = (const int*)d_in[1];     // [4096,4096] int32 codes
    const float* sc   = (const float*)d_in[2];   // [4096,64] fp32
    const float* bias = (const float*)d_in[3];   // [4096]
    const float* lA   = (const float*)d_in[4];   // [16,4096]
    const float* lB   = (const float*)d_in[5];   // [4096,16]
    float* out = (float*)d_out;                  // [4,2048,4096] fp32

    // workspace: W'_bf16 only (32 MB) -- xb intermediate eliminated
    __hip_bfloat16* wb = (__hip_bfloat16*)d_ws;

    // allow 128 KiB dynamic LDS for the 8-phase GEMM (host-side, capture-safe)
    static bool attr_done = false;
    if (!attr_done) {
        (void)hipFuncSetAttribute((const void*)gemm256_8ph,
                                  hipFuncAttributeMaxDynamicSharedMemorySize, 131072);
        attr_done = true;
    }

    dequant_lora<<<2048, 256, 0, stream>>>(qc, sc, lA, lB, wb);
    gemm256_8ph<<<dim3(512), dim3(512), 131072, stream>>>(x, wb, bias, out);
}

// Round 6
// 489.490 us; speedup vs baseline: 1.0963x; 1.0963x over previous
//
#include <hip/hip_runtime.h>
#include <hip/hip_bf16.h>

// Problem constants (fixed by reference)
#define IN_F   4096
#define OUT_F  4096
#define RANK   16
#define M_TOK  8192          // 4 * 2048 tokens
#define SCALING 2.0f         // ALPHA / RANK = 32/16

typedef __attribute__((ext_vector_type(8))) short short8;   // 8 bf16 = 4 VGPRs
typedef __attribute__((ext_vector_type(4))) float f32x4;
typedef __attribute__((ext_vector_type(4))) float fvec4;
typedef __attribute__((ext_vector_type(4))) int   ivec4;
typedef __attribute__((ext_vector_type(4))) unsigned int uvec4;

// ---------------------------------------------------------------------------
// cvt: x fp32 -> bf16, grid-stride streaming (192 MB HBM).  Best-measured
// prep split (r2: cvt+dequant ~65 us combined vs 77 us fused).
// ---------------------------------------------------------------------------
__global__ __launch_bounds__(256) void cvt_x(const float* __restrict__ x,
                                             __hip_bfloat16* __restrict__ xb) {
    const size_t nvec = (size_t)M_TOK * IN_F / 8;
    const size_t stride = (size_t)gridDim.x * 256;
    for (size_t idx = (size_t)blockIdx.x * 256 + threadIdx.x; idx < nvec; idx += stride) {
        const size_t i = idx * 8;
        fvec4 a = __builtin_nontemporal_load((const fvec4*)(x + i));
        fvec4 b = __builtin_nontemporal_load((const fvec4*)(x + i + 4));
        union { uvec4 u; __hip_bfloat16 h[8]; } p;
        p.h[0] = __float2bfloat16(a.x);
        p.h[1] = __float2bfloat16(a.y);
        p.h[2] = __float2bfloat16(a.z);
        p.h[3] = __float2bfloat16(a.w);
        p.h[4] = __float2bfloat16(b.x);
        p.h[5] = __float2bfloat16(b.y);
        p.h[6] = __float2bfloat16(b.z);
        p.h[7] = __float2bfloat16(b.w);
        *(uvec4*)(xb + i) = p.u;              // normal store: GEMM re-reads 16x
    }
}

// ---------------------------------------------------------------------------
// dequant + LoRA fold: W'[o,i] = (q-8)*scale + 2*(lB@lA)[o,i].
// Thread owns 4 columns; lA slice in 16 fvec4 registers; 8 o-rows/block with
// all 8 q-loads hoisted.  2048 blocks x 256 threads (~25 us measured fit).
// ---------------------------------------------------------------------------
__global__ __launch_bounds__(256) void dequant_lora(const int* __restrict__ q,
                                                    const float* __restrict__ sc,
                                                    const float* __restrict__ lA,
                                                    const float* __restrict__ lB,
                                                    __hip_bfloat16* __restrict__ W) {
    const int tid = threadIdx.x;
    const int id  = blockIdx.x;              // 0..2047
    const int c0  = (id & 3) * 1024 + tid * 4;
    const int o0  = (id >> 2) * 8;

    ivec4 qv[8];
#pragma unroll
    for (int oo = 0; oo < 8; ++oo)           // all 8 HBM loads in flight
        qv[oo] = __builtin_nontemporal_load(
            (const ivec4*)(q + (size_t)(o0 + oo) * IN_F + c0));

    float sv[8];
#pragma unroll
    for (int oo = 0; oo < 8; ++oo)
        sv[oo] = sc[(o0 + oo) * (IN_F / 64) + (c0 >> 6)];

    fvec4 a[RANK];
#pragma unroll
    for (int r = 0; r < RANK; ++r)           // L2-resident after first touch
        a[r] = *(const fvec4*)(lA + (size_t)r * IN_F + c0);

#pragma unroll
    for (int oo = 0; oo < 8; ++oo) {
        const float* lbo = lB + (size_t)(o0 + oo) * RANK;   // uniform -> SMEM
        float l0 = 0.f, l1 = 0.f, l2 = 0.f, l3 = 0.f;
#pragma unroll
        for (int r = 0; r < RANK; ++r) {
            const float br = lbo[r];
            l0 += br * a[r].x; l1 += br * a[r].y;
            l2 += br * a[r].z; l3 += br * a[r].w;
        }
        const float s = sv[oo];
        union { ushort4 u; __hip_bfloat16 h[4]; } p;
        p.h[0] = __float2bfloat16((float)(qv[oo].x - 8) * s + SCALING * l0);
        p.h[1] = __float2bfloat16((float)(qv[oo].y - 8) * s + SCALING * l1);
        p.h[2] = __float2bfloat16((float)(qv[oo].z - 8) * s + SCALING * l2);
        p.h[3] = __float2bfloat16((float)(qv[oo].w - 8) * s + SCALING * l3);
        *(ushort4*)(W + (size_t)(o0 + oo) * IN_F + c0) = p.u;
    }
}

// ---------------------------------------------------------------------------
// GEMM: C[M,N] = A[M,K](bf16) * B[N,K]^T(bf16) + bias
// 256x256 tile, BK=64, 512 threads = 8 waves (2M x 4N), 8-phase schedule with
// counted vmcnt (T3+T4), st_16x32 LDS swizzle (T2), setprio (T5), XCD 8x8
// chunk (T1).  Round-3 verified body (244 us, MfmaUtil 50, conflicts 0).
//
// ROUND-6 CHANGE (staging depth only; barrier structure byte-identical):
// all staging now targets tile t+2 -> every load has 4-5 phases of latency
// cover instead of 2.  Per K-tile t:
//   ph0: ds A(mh0)x8 + B(nh0)x4          ; 16 MFMA
//   ph1: ds B(nh1)x4                     ; 16 MFMA
//   ph2: ds A(mh1)x8; stage B(t+2) x4 -> cb B region (cb-B reads done ph1)
//   ph3: stage A(t+2) x4 -> cb A region (cb-A reads done ph2); vmcnt(8); bar
// vmcnt ledger (at t ph3 wait): queue = [B(t+1)x4 (t-1 ph2), A(t+1)x4
// (t-1 ph3), B(t+2)x4 (t ph2), A(t+2)x4 (t ph3)] = 16; vmcnt(8) lands
// A(t+1)+B(t+1), leaves tile t+2's 8 in flight.  Never 0 in the loop.
// WAR safety: B(t+2) issue follows ph1's closing barrier (all waves' cb-B
// reads done); A(t+2) issue follows ph2's closing barrier (cb-A reads done).
// Landing order: tile t+2's loads are covered by t+1 ph3's vmcnt(8)+barrier
// before any t+2 ph0 read.  Tail staging wraps k-offset (&63): valid memory,
// overwrites only post-final-read regions.
// ---------------------------------------------------------------------------

__device__ __forceinline__ void load_lds16(const void* g, void* l) {
    __builtin_amdgcn_global_load_lds(
        (const __attribute__((address_space(1))) unsigned int*)g,
        (__attribute__((address_space(3))) unsigned int*)l, 16, 0, 0);
}

#define MFMA_BF16 __builtin_amdgcn_mfma_f32_16x16x32_bf16

__global__ __launch_bounds__(512, 2) void gemm256_8ph(const __hip_bfloat16* __restrict__ A,
                                                      const __hip_bfloat16* __restrict__ B,
                                                      const float* __restrict__ bias,
                                                      float* __restrict__ C) {
    extern __shared__ __align__(16) char lds[];

    const int tid  = threadIdx.x;
    const int lane = tid & 63;
    const int wave = tid >> 6;

    // T1: XCD swizzle, 8x8 square chunk per XCD (512 wgs % 8 == 0, bijective).
    const int xcd = blockIdx.x & 7;
    const int w64 = blockIdx.x >> 3;               // 0..63 within XCD
    const int tm  = (xcd >> 1) * 8 + (w64 >> 3);   // 0..31 M-tiles
    const int tn  = (xcd & 1) * 8 + (w64 & 7);     // 0..15 N-tiles

    const __hip_bfloat16* Ab = A + (size_t)tm * 256 * IN_F;
    const __hip_bfloat16* Bb = B + (size_t)tn * 256 * IN_F;

    // Staging source (inverse-swizzled, matches read-side XOR):
    // lane l supplies 16B: row (l>>2), elem ((l&3)*8) ^ (l>=32 ? 16 : 0).
    const int    c0   = ((lane & 3) * 8) ^ ((lane >= 32) ? 16 : 0);
    const size_t off0 = (size_t)((wave >> 1) * 16 + (lane >> 2)) * IN_F
                      + (size_t)((wave & 1) * 32 + c0);

    // Global source stream bases (per-lane, advance by scalar t-offset only)
    const __hip_bfloat16* qA0 = Ab + off0;
    const __hip_bfloat16* qA1 = Ab + (size_t)128 * IN_F + off0;
    const __hip_bfloat16* qB0 = Bb + off0;
    const __hip_bfloat16* qB1 = Bb + (size_t)128 * IN_F + off0;

    // Swizzled ds_read lane offset within a 1 KiB subtile:
    // logical byte = (lane&15)*64 + (lane>>4)*16 ; swizzle XORs bit5 with bit9.
    const int flo = (lane & 15) * 64 + (((lane >> 4) * 16) ^ ((lane & 8) << 2));

    const int ah = wave >> 2;          // A half this wave reads (rows)
    const int bh = (wave >> 1) & 1;    // B half this wave reads (cols)
    const int bs = (wave & 1) * 4;     // B subtile-row base within half

    // Pre-folded LDS read bases per buffer: every read is base + literal.
    const char* aRd[2] = { lds + ah * 16384 + flo,
                           lds + 65536 + ah * 16384 + flo };
    const char* bRd[2] = { lds + 32768 + bh * 16384 + bs * 2048 + flo,
                           lds + 65536 + 32768 + bh * 16384 + bs * 2048 + flo };

    const int wv1024 = wave * 1024;    // staging dest lane-group base

#define STAGE2(ps, te, LO) do {                                             \
        const __hip_bfloat16* g_ = (ps) + (te);                             \
        load_lds16(g_,              lds + (LO) + wv1024);                   \
        load_lds16(g_ + 64 * IN_F,  lds + (LO) + 8192 + wv1024);            \
    } while (0)

    // ---- prologue: tiles 0 and 1 fully staged (16 loads) ----
    STAGE2(qB0, 0,  32768);
    STAGE2(qB1, 0,  49152);
    STAGE2(qA0, 0,  0);
    STAGE2(qA1, 0,  16384);
    STAGE2(qB0, 64, 65536 + 32768);
    STAGE2(qB1, 64, 65536 + 49152);
    STAGE2(qA0, 64, 65536 + 0);
    STAGE2(qA1, 64, 65536 + 16384);
    asm volatile("s_waitcnt vmcnt(8)" ::: "memory");   // tile0 landed; tile1 in flight
    __builtin_amdgcn_s_barrier();

    short8 aF[4][2], bAf[2][2], bBf[2][2];
    f32x4 acc[8][4] = {};

#define TILE(T, CBI) do {                                                          \
        const int t2e = (((T) + 2) & 63) << 6;   /* elem offset of tile T+2 */     \
        /* ---------- phase 0: quadrant (mh0, nh0) ---------- */                   \
        _Pragma("unroll")                                                          \
        for (int i = 0; i < 4; ++i)                                                \
            _Pragma("unroll")                                                      \
            for (int kk = 0; kk < 2; ++kk)                                         \
                aF[i][kk] = *(const short8*)(aRd[CBI] + (i * 2 + kk) * 1024);      \
        _Pragma("unroll")                                                          \
        for (int j = 0; j < 2; ++j)                                                \
            _Pragma("unroll")                                                      \
            for (int kk = 0; kk < 2; ++kk)                                         \
                bAf[j][kk] = *(const short8*)(bRd[CBI] + (j * 2 + kk) * 1024);     \
        __builtin_amdgcn_s_barrier();                                              \
        __builtin_amdgcn_s_setprio(1);                                             \
        _Pragma("unroll")                                                          \
        for (int i = 0; i < 4; ++i)                                                \
            _Pragma("unroll")                                                      \
            for (int j = 0; j < 2; ++j)                                            \
                _Pragma("unroll")                                                  \
                for (int kk = 0; kk < 2; ++kk)                                     \
                    acc[i][j] = MFMA_BF16(aF[i][kk], bAf[j][kk], acc[i][j], 0,0,0);\
        __builtin_amdgcn_s_setprio(0);                                             \
        __builtin_amdgcn_s_barrier();                                              \
        /* ---------- phase 1: quadrant (mh0, nh1) ---------- */                   \
        _Pragma("unroll")                                                          \
        for (int j = 0; j < 2; ++j)                                                \
            _Pragma("unroll")                                                      \
            for (int kk = 0; kk < 2; ++kk)                                         \
                bBf[j][kk] = *(const short8*)(bRd[CBI] + 4096 + (j*2+kk) * 1024);  \
        __builtin_amdgcn_s_barrier();                                              \
        __builtin_amdgcn_s_setprio(1);                                             \
        _Pragma("unroll")                                                          \
        for (int i = 0; i < 4; ++i)                                                \
            _Pragma("unroll")                                                      \
            for (int j = 0; j < 2; ++j)                                            \
                _Pragma("unroll")                                                  \
                for (int kk = 0; kk < 2; ++kk)                                     \
                    acc[i][2+j] = MFMA_BF16(aF[i][kk], bBf[j][kk], acc[i][2+j],0,0,0);\
        __builtin_amdgcn_s_setprio(0);                                             \
        __builtin_amdgcn_s_barrier();                                              \
        /* ---------- phase 2: quadrant (mh1, nh1) ---------- */                   \
        _Pragma("unroll")                                                          \
        for (int i = 0; i < 4; ++i)                                                \
            _Pragma("unroll")                                                      \
            for (int kk = 0; kk < 2; ++kk)                                         \
                aF[i][kk] = *(const short8*)(aRd[CBI] + 8192 + (i*2+kk) * 1024);   \
        STAGE2(qB0, t2e, (CBI) * 65536 + 32768);   /* cb-B reads done ph1 */       \
        STAGE2(qB1, t2e, (CBI) * 65536 + 49152);                                   \
        __builtin_amdgcn_s_barrier();                                              \
        __builtin_amdgcn_s_setprio(1);                                             \
        _Pragma("unroll")                                                          \
        for (int i = 0; i < 4; ++i)                                                \
            _Pragma("unroll")                                                      \
            for (int j = 0; j < 2; ++j)                                            \
                _Pragma("unroll")                                                  \
                for (int kk = 0; kk < 2; ++kk)                                     \
                    acc[4+i][2+j] = MFMA_BF16(aF[i][kk], bBf[j][kk], acc[4+i][2+j],0,0,0);\
        __builtin_amdgcn_s_setprio(0);                                             \
        __builtin_amdgcn_s_barrier();                                              \
        /* ---------- phase 3: quadrant (mh1, nh0) ---------- */                   \
        STAGE2(qA0, t2e, (CBI) * 65536 + 0);       /* cb-A reads done ph2 */       \
        STAGE2(qA1, t2e, (CBI) * 65536 + 16384);                                   \
        asm volatile("s_waitcnt vmcnt(8)" ::: "memory");  /* tile T+1 landed */    \
        __builtin_amdgcn_s_barrier();                     /* publish to all */     \
        __builtin_amdgcn_s_setprio(1);                                             \
        _Pragma("unroll")                                                          \
        for (int i = 0; i < 4; ++i)                                                \
            _Pragma("unroll")                                                      \
            for (int j = 0; j < 2; ++j)                                            \
                _Pragma("unroll")                                                  \
                for (int kk = 0; kk < 2; ++kk)                                     \
                    acc[4+i][j] = MFMA_BF16(aF[i][kk], bAf[j][kk], acc[4+i][j],0,0,0);\
        __builtin_amdgcn_s_setprio(0);                                             \
        __builtin_amdgcn_s_barrier();                                              \
    } while (0)

    for (int tt = 0; tt < 32; ++tt) {      // 2 K-tiles per iter: literal buffers
        TILE(2 * tt,     0);
        TILE(2 * tt + 1, 1);
    }
    asm volatile("s_waitcnt vmcnt(0)" ::: "memory");  // drain wrapped prefetches

    // ---- epilogue: D[row=(lane>>4)*4+r][col=lane&15] per 16x16 frag; +bias ----
    const int qd = lane >> 4;
    const int cl = lane & 15;
    const size_t m_base = (size_t)tm * 256 + (size_t)ah * 128;
    const int    n_base = tn * 256 + (wave & 3) * 64;
#pragma unroll
    for (int fn = 0; fn < 4; ++fn) {
        const int n = n_base + fn * 16 + cl;
        const float bv = bias[n];
#pragma unroll
        for (int fm = 0; fm < 8; ++fm) {
            const size_t m0 = m_base + fm * 16 + qd * 4;
#pragma unroll
            for (int r = 0; r < 4; ++r)
                __builtin_nontemporal_store(acc[fm][fn][r] + bv,
                                            &C[(m0 + r) * OUT_F + n]);
        }
    }
#undef STAGE2
#undef TILE
}

// ---------------------------------------------------------------------------
extern "C" void kernel_launch(void* const* d_in, const int* in_sizes, int n_in,
                              void* d_out, int out_size, void* d_ws, size_t ws_size,
                              hipStream_t stream) {
    const float* x    = (const float*)d_in[0];   // [4,2048,4096] fp32
    const int*   qc   = (const int*)d_in[1];     // [4096,4096] int32 codes
    const float* sc   = (const float*)d_in[2];   // [4096,64] fp32
    const float* bias = (const float*)d_in[3];   // [4096]
    const float* lA   = (const float*)d_in[4];   // [16,4096]
    const float* lB   = (const float*)d_in[5];   // [4096,16]
    float* out = (float*)d_out;                  // [4,2048,4096] fp32

    // workspace: x_bf16 (64 MB) + W'_bf16 (32 MB) = 96 MB
    __hip_bfloat16* xb = (__hip_bfloat16*)d_ws;
    __hip_bfloat16* wb = xb + (size_t)M_TOK * IN_F;

    // allow 128 KiB dynamic LDS for the 8-phase GEMM (host-side, capture-safe)
    static bool attr_done = false;
    if (!attr_done) {
        (void)hipFuncSetAttribute((const void*)gemm256_8ph,
                                  hipFuncAttributeMaxDynamicSharedMemorySize, 131072);
        attr_done = true;
    }

    cvt_x<<<2048, 256, 0, stream>>>(x, xb);
    dequant_lora<<<2048, 256, 0, stream>>>(qc, sc, lA, lB, wb);
    gemm256_8ph<<<dim3(512), dim3(512), 131072, stream>>>(xb, wb, bias, out);
}

// Round 7
// 474.474 us; speedup vs baseline: 1.1310x; 1.0316x over previous
//
#include <hip/hip_runtime.h>
#include <hip/hip_bf16.h>

// Problem constants (fixed by reference)
#define IN_F   4096
#define OUT_F  4096
#define RANK   16
#define M_TOK  8192          // 4 * 2048 tokens
#define SCALING 2.0f         // ALPHA / RANK = 32/16

typedef __attribute__((ext_vector_type(8))) short short8;   // 8 bf16 = 4 VGPRs
typedef __attribute__((ext_vector_type(4))) float f32x4;
typedef __attribute__((ext_vector_type(4))) float fvec4;
typedef __attribute__((ext_vector_type(4))) int   ivec4;
typedef __attribute__((ext_vector_type(4))) unsigned int uvec4;

// ---------------------------------------------------------------------------
// cvt: x fp32 -> bf16, grid-stride streaming (192 MB HBM).
// ---------------------------------------------------------------------------
__global__ __launch_bounds__(256) void cvt_x(const float* __restrict__ x,
                                             __hip_bfloat16* __restrict__ xb) {
    const size_t nvec = (size_t)M_TOK * IN_F / 8;
    const size_t stride = (size_t)gridDim.x * 256;
    for (size_t idx = (size_t)blockIdx.x * 256 + threadIdx.x; idx < nvec; idx += stride) {
        const size_t i = idx * 8;
        fvec4 a = __builtin_nontemporal_load((const fvec4*)(x + i));
        fvec4 b = __builtin_nontemporal_load((const fvec4*)(x + i + 4));
        union { uvec4 u; __hip_bfloat16 h[8]; } p;
        p.h[0] = __float2bfloat16(a.x);
        p.h[1] = __float2bfloat16(a.y);
        p.h[2] = __float2bfloat16(a.z);
        p.h[3] = __float2bfloat16(a.w);
        p.h[4] = __float2bfloat16(b.x);
        p.h[5] = __float2bfloat16(b.y);
        p.h[6] = __float2bfloat16(b.z);
        p.h[7] = __float2bfloat16(b.w);
        *(uvec4*)(xb + i) = p.u;              // normal store: GEMM re-reads 16x
    }
}

// ---------------------------------------------------------------------------
// dequant + LoRA fold: W'[o,i] = (q-8)*scale + 2*(lB@lA)[o,i].
// Thread owns 4 columns; lA slice in 16 fvec4 registers; 8 o-rows/block with
// all 8 q-loads hoisted.  2048 blocks x 256 threads (~25 us fitted).
// ---------------------------------------------------------------------------
__global__ __launch_bounds__(256) void dequant_lora(const int* __restrict__ q,
                                                    const float* __restrict__ sc,
                                                    const float* __restrict__ lA,
                                                    const float* __restrict__ lB,
                                                    __hip_bfloat16* __restrict__ W) {
    const int tid = threadIdx.x;
    const int id  = blockIdx.x;              // 0..2047
    const int c0  = (id & 3) * 1024 + tid * 4;
    const int o0  = (id >> 2) * 8;

    ivec4 qv[8];
#pragma unroll
    for (int oo = 0; oo < 8; ++oo)           // all 8 HBM loads in flight
        qv[oo] = __builtin_nontemporal_load(
            (const ivec4*)(q + (size_t)(o0 + oo) * IN_F + c0));

    float sv[8];
#pragma unroll
    for (int oo = 0; oo < 8; ++oo)
        sv[oo] = sc[(o0 + oo) * (IN_F / 64) + (c0 >> 6)];

    fvec4 a[RANK];
#pragma unroll
    for (int r = 0; r < RANK; ++r)           // L2-resident after first touch
        a[r] = *(const fvec4*)(lA + (size_t)r * IN_F + c0);

#pragma unroll
    for (int oo = 0; oo < 8; ++oo) {
        const float* lbo = lB + (size_t)(o0 + oo) * RANK;   // uniform -> SMEM
        float l0 = 0.f, l1 = 0.f, l2 = 0.f, l3 = 0.f;
#pragma unroll
        for (int r = 0; r < RANK; ++r) {
            const float br = lbo[r];
            l0 += br * a[r].x; l1 += br * a[r].y;
            l2 += br * a[r].z; l3 += br * a[r].w;
        }
        const float s = sv[oo];
        union { ushort4 u; __hip_bfloat16 h[4]; } p;
        p.h[0] = __float2bfloat16((float)(qv[oo].x - 8) * s + SCALING * l0);
        p.h[1] = __float2bfloat16((float)(qv[oo].y - 8) * s + SCALING * l1);
        p.h[2] = __float2bfloat16((float)(qv[oo].z - 8) * s + SCALING * l2);
        p.h[3] = __float2bfloat16((float)(qv[oo].w - 8) * s + SCALING * l3);
        *(ushort4*)(W + (size_t)(o0 + oo) * IN_F + c0) = p.u;
    }
}

// ---------------------------------------------------------------------------
// GEMM: C[M,N] = A[M,K](bf16) * B[N,K]^T(bf16) + bias
// EXACT round-3 verified body (244 us, MfmaUtil 50%, conflicts 0): 256x256
// tile, BK=64, 8 waves (2Mx4N), counted vmcnt (T3+T4), st_16x32 swizzle (T2),
// setprio (T5), XCD 8x8 chunk (T1), literal double-buffer via 2-tile unroll.
//
// ROUND-7 CHANGE (single edit, m201-faithful vmcnt placement): ph3's
// s_waitcnt vmcnt(4) moves from BEFORE the phase barrier to AFTER the MFMA
// cluster (before the closing barrier).  ph3's MFMAs consume only tile-t LDS
// data (already resident), so they legally run while tile t+1's loads land;
// the closing barrier still publishes the landing before any t+1 ph0 read.
// sched_barrier(0) pins the MFMAs above the wait (compiler may not sink them).
//
// Phase schedule per K-tile t:
//   ph0: ds A(mh0)x8 + B(nh0)x4; stage A0(t+1)->other buf      ; 16 MFMA
//   ph1: ds B(nh1)x4;            stage A1(t+1)->other buf      ; 16 MFMA
//   ph2: ds A(mh1)x8;            stage B0(t+2)->THIS buf (dead); 16 MFMA
//   ph3: stage B1(t+2); bar; 16 MFMA; vmcnt(4); bar
// vmcnt ledger: newest load needed for t+1 = A1(t+1) (issued ph1); loads
// issued after it = B0,B1(t+2) = 4 -> s_waitcnt vmcnt(4). Never 0 in loop.
// ---------------------------------------------------------------------------

__device__ __forceinline__ void load_lds16(const void* g, void* l) {
    __builtin_amdgcn_global_load_lds(
        (const __attribute__((address_space(1))) unsigned int*)g,
        (__attribute__((address_space(3))) unsigned int*)l, 16, 0, 0);
}

#define MFMA_BF16 __builtin_amdgcn_mfma_f32_16x16x32_bf16

__global__ __launch_bounds__(512, 2) void gemm256_8ph(const __hip_bfloat16* __restrict__ A,
                                                      const __hip_bfloat16* __restrict__ B,
                                                      const float* __restrict__ bias,
                                                      float* __restrict__ C) {
    extern __shared__ __align__(16) char lds[];

    const int tid  = threadIdx.x;
    const int lane = tid & 63;
    const int wave = tid >> 6;

    // T1: XCD swizzle, 8x8 square chunk per XCD (512 wgs % 8 == 0, bijective).
    const int xcd = blockIdx.x & 7;
    const int w64 = blockIdx.x >> 3;               // 0..63 within XCD
    const int tm  = (xcd >> 1) * 8 + (w64 >> 3);   // 0..31 M-tiles
    const int tn  = (xcd & 1) * 8 + (w64 & 7);     // 0..15 N-tiles

    const __hip_bfloat16* Ab = A + (size_t)tm * 256 * IN_F;
    const __hip_bfloat16* Bb = B + (size_t)tn * 256 * IN_F;

    // Staging source (inverse-swizzled, matches read-side XOR):
    // lane l supplies 16B: row (l>>2), elem ((l&3)*8) ^ (l>=32 ? 16 : 0).
    const int    c0   = ((lane & 3) * 8) ^ ((lane >= 32) ? 16 : 0);
    const size_t off0 = (size_t)((wave >> 1) * 16 + (lane >> 2)) * IN_F
                      + (size_t)((wave & 1) * 32 + c0);

    // Global source stream bases (per-lane, advance by scalar t-offset only)
    const __hip_bfloat16* qA0 = Ab + off0;
    const __hip_bfloat16* qA1 = Ab + (size_t)128 * IN_F + off0;
    const __hip_bfloat16* qB0 = Bb + off0;
    const __hip_bfloat16* qB1 = Bb + (size_t)128 * IN_F + off0;

    // Swizzled ds_read lane offset within a 1 KiB subtile:
    // logical byte = (lane&15)*64 + (lane>>4)*16 ; swizzle XORs bit5 with bit9.
    const int flo = (lane & 15) * 64 + (((lane >> 4) * 16) ^ ((lane & 8) << 2));

    const int ah = wave >> 2;          // A half this wave reads (rows)
    const int bh = (wave >> 1) & 1;    // B half this wave reads (cols)
    const int bs = (wave & 1) * 4;     // B subtile-row base within half

    // Pre-folded LDS read bases per buffer: every read is base + literal.
    const char* aRd[2] = { lds + ah * 16384 + flo,
                           lds + 65536 + ah * 16384 + flo };
    const char* bRd[2] = { lds + 32768 + bh * 16384 + bs * 2048 + flo,
                           lds + 65536 + 32768 + bh * 16384 + bs * 2048 + flo };

    const int wv1024 = wave * 1024;    // staging dest lane-group base

#define STAGE2(ps, te, LO) do {                                             \
        const __hip_bfloat16* g_ = (ps) + (te);                             \
        load_lds16(g_,              lds + (LO) + wv1024);                   \
        load_lds16(g_ + 64 * IN_F,  lds + (LO) + 8192 + wv1024);            \
    } while (0)

    // ---- prologue: B0(0) B1(0) A0(0) A1(0) B0(1) B1(1)  (12 loads) ----
    STAGE2(qB0, 0,  32768);
    STAGE2(qB1, 0,  49152);
    STAGE2(qA0, 0,  0);
    STAGE2(qA1, 0,  16384);
    STAGE2(qB0, 64, 65536 + 32768);
    STAGE2(qB1, 64, 65536 + 49152);
    asm volatile("s_waitcnt vmcnt(4)" ::: "memory");   // tile0 landed; B(1) in flight
    __builtin_amdgcn_s_barrier();

    short8 aF[4][2], bAf[2][2], bBf[2][2];
    f32x4 acc[8][4] = {};

#define TILE(T, CBI) do {                                                          \
        const int t1e = (((T) + 1) & 63) << 6;   /* elem offset of tile T+1 */     \
        const int t2e = (((T) + 2) & 63) << 6;                                     \
        /* ---------- phase 0: quadrant (mh0, nh0) ---------- */                   \
        _Pragma("unroll")                                                          \
        for (int i = 0; i < 4; ++i)                                                \
            _Pragma("unroll")                                                      \
            for (int kk = 0; kk < 2; ++kk)                                         \
                aF[i][kk] = *(const short8*)(aRd[CBI] + (i * 2 + kk) * 1024);      \
        _Pragma("unroll")                                                          \
        for (int j = 0; j < 2; ++j)                                                \
            _Pragma("unroll")                                                      \
            for (int kk = 0; kk < 2; ++kk)                                         \
                bAf[j][kk] = *(const short8*)(bRd[CBI] + (j * 2 + kk) * 1024);     \
        STAGE2(qA0, t1e, ((CBI) ^ 1) * 65536);                                     \
        __builtin_amdgcn_s_barrier();                                              \
        __builtin_amdgcn_s_setprio(1);                                             \
        _Pragma("unroll")                                                          \
        for (int i = 0; i < 4; ++i)                                                \
            _Pragma("unroll")                                                      \
            for (int j = 0; j < 2; ++j)                                            \
                _Pragma("unroll")                                                  \
                for (int kk = 0; kk < 2; ++kk)                                     \
                    acc[i][j] = MFMA_BF16(aF[i][kk], bAf[j][kk], acc[i][j], 0,0,0);\
        __builtin_amdgcn_s_setprio(0);                                             \
        __builtin_amdgcn_s_barrier();                                              \
        /* ---------- phase 1: quadrant (mh0, nh1) ---------- */                   \
        _Pragma("unroll")                                                          \
        for (int j = 0; j < 2; ++j)                                                \
            _Pragma("unroll")                                                      \
            for (int kk = 0; kk < 2; ++kk)                                         \
                bBf[j][kk] = *(const short8*)(bRd[CBI] + 4096 + (j*2+kk) * 1024);  \
        STAGE2(qA1, t1e, ((CBI) ^ 1) * 65536 + 16384);                             \
        __builtin_amdgcn_s_barrier();                                              \
        __builtin_amdgcn_s_setprio(1);                                             \
        _Pragma("unroll")                                                          \
        for (int i = 0; i < 4; ++i)                                                \
            _Pragma("unroll")                                                      \
            for (int j = 0; j < 2; ++j)                                            \
                _Pragma("unroll")                                                  \
                for (int kk = 0; kk < 2; ++kk)                                     \
                    acc[i][2+j] = MFMA_BF16(aF[i][kk], bBf[j][kk], acc[i][2+j],0,0,0);\
        __builtin_amdgcn_s_setprio(0);                                             \
        __builtin_amdgcn_s_barrier();                                              \
        /* ---------- phase 2: quadrant (mh1, nh1) ---------- */                   \
        _Pragma("unroll")                                                          \
        for (int i = 0; i < 4; ++i)                                                \
            _Pragma("unroll")                                                      \
            for (int kk = 0; kk < 2; ++kk)                                         \
                aF[i][kk] = *(const short8*)(aRd[CBI] + 8192 + (i*2+kk) * 1024);   \
        STAGE2(qB0, t2e, (CBI) * 65536 + 32768);   /* dead after ph1 */            \
        __builtin_amdgcn_s_barrier();                                              \
        __builtin_amdgcn_s_setprio(1);                                             \
        _Pragma("unroll")                                                          \
        for (int i = 0; i < 4; ++i)                                                \
            _Pragma("unroll")                                                      \
            for (int j = 0; j < 2; ++j)                                            \
                _Pragma("unroll")                                                  \
                for (int kk = 0; kk < 2; ++kk)                                     \
                    acc[4+i][2+j] = MFMA_BF16(aF[i][kk], bBf[j][kk], acc[4+i][2+j],0,0,0);\
        __builtin_amdgcn_s_setprio(0);                                             \
        __builtin_amdgcn_s_barrier();                                              \
        /* ---------- phase 3: quadrant (mh1, nh0) ---------- */                   \
        STAGE2(qB1, t2e, (CBI) * 65536 + 49152);                                   \
        __builtin_amdgcn_s_barrier();                                              \
        __builtin_amdgcn_s_setprio(1);                                             \
        _Pragma("unroll")                                                          \
        for (int i = 0; i < 4; ++i)                                                \
            _Pragma("unroll")                                                      \
            for (int j = 0; j < 2; ++j)                                            \
                _Pragma("unroll")                                                  \
                for (int kk = 0; kk < 2; ++kk)                                     \
                    acc[4+i][j] = MFMA_BF16(aF[i][kk], bAf[j][kk], acc[4+i][j],0,0,0);\
        __builtin_amdgcn_s_setprio(0);                                             \
        __builtin_amdgcn_sched_barrier(0);   /* keep MFMAs above the wait */       \
        asm volatile("s_waitcnt vmcnt(4)" ::: "memory");  /* t+1 landed (hidden */ \
        __builtin_amdgcn_s_barrier();        /* under MFMAs); publish to all */    \
    } while (0)

    for (int tt = 0; tt < 32; ++tt) {      // 2 K-tiles per iter: literal buffers
        TILE(2 * tt,     0);
        TILE(2 * tt + 1, 1);
    }
    asm volatile("s_waitcnt vmcnt(0)" ::: "memory");  // drain wrapped prefetches

    // ---- epilogue: D[row=(lane>>4)*4+r][col=lane&15] per 16x16 frag; +bias ----
    const int qd = lane >> 4;
    const int cl = lane & 15;
    const size_t m_base = (size_t)tm * 256 + (size_t)ah * 128;
    const int    n_base = tn * 256 + (wave & 3) * 64;
#pragma unroll
    for (int fn = 0; fn < 4; ++fn) {
        const int n = n_base + fn * 16 + cl;
        const float bv = bias[n];
#pragma unroll
        for (int fm = 0; fm < 8; ++fm) {
            const size_t m0 = m_base + fm * 16 + qd * 4;
#pragma unroll
            for (int r = 0; r < 4; ++r)
                __builtin_nontemporal_store(acc[fm][fn][r] + bv,
                                            &C[(m0 + r) * OUT_F + n]);
        }
    }
#undef STAGE2
#undef TILE
}

// ---------------------------------------------------------------------------
extern "C" void kernel_launch(void* const* d_in, const int* in_sizes, int n_in,
                              void* d_out, int out_size, void* d_ws, size_t ws_size,
                              hipStream_t stream) {
    const float* x    = (const float*)d_in[0];   // [4,2048,4096] fp32
    const int*   qc   = (const int*)d_in[1];     // [4096,4096] int32 codes
    const float* sc   = (const float*)d_in[2];   // [4096,64] fp32
    const float* bias = (const float*)d_in[3];   // [4096]
    const float* lA   = (const float*)d_in[4];   // [16,4096]
    const float* lB   = (const float*)d_in[5];   // [4096,16]
    float* out = (float*)d_out;                  // [4,2048,4096] fp32

    // workspace: x_bf16 (64 MB) + W'_bf16 (32 MB) = 96 MB
    __hip_bfloat16* xb = (__hip_bfloat16*)d_ws;
    __hip_bfloat16* wb = xb + (size_t)M_TOK * IN_F;

    // allow 128 KiB dynamic LDS for the 8-phase GEMM (host-side, capture-safe)
    static bool attr_done = false;
    if (!attr_done) {
        (void)hipFuncSetAttribute((const void*)gemm256_8ph,
                                  hipFuncAttributeMaxDynamicSharedMemorySize, 131072);
        attr_done = true;
    }

    cvt_x<<<2048, 256, 0, stream>>>(x, xb);
    dequant_lora<<<2048, 256, 0, stream>>>(qc, sc, lA, lB, wb);
    gemm256_8ph<<<dim3(512), dim3(512), 131072, stream>>>(xb, wb, bias, out);
}